// Round 14
// baseline (129.551 us; speedup 1.0000x reference)
//
#include <hip/hip_runtime.h>

// MaskPyramids R14: NONTEMPORAL zero-fill + sparse window paint.
// Index chain (VERIFIED bit-exact R11-R13, absmax=0.0): XLA rcp-multiply:
//   x = (float)p * 0.005f;  lh_L = (int)rintf(x * (float)H_L)
// R13 post-mortem: graph-captured hipMemsetAsync ran at the SAME ~2.4 TB/s
// as a plain float4 store kernel (dur 116.7 -> 117.7) => memset-in-graph
// does not use the fast fill path; ordinary stores pay RFO (line fetched
// from HBM before write => 2x traffic). Fix: __builtin_nontemporal_store
// (global_store_dwordx4 nt) = streaming store, no write-allocate:
//   pass 1: nt float4 zero-fill, 109 MB @ ~6 TB/s   ~18 us
//   pass 2: paint 512x5 blocks, <=784 cells each (~6.5 MB)  ~3 us

#define G 28
#define CTR 13
#define ROW 53294          // 40000+10000+2500+625+169 floats per instance
#define FILL_BLOCKS 26647  // 512*ROW/4/256, exact

typedef float vfloat4 __attribute__((ext_vector_type(4)));

__global__ __launch_bounds__(256) void fill_zero_nt_kernel(vfloat4* __restrict__ out4) {
  const int idx = blockIdx.x * 256 + threadIdx.x;   // grid sized exactly
  vfloat4 z = {0.f, 0.f, 0.f, 0.f};
  __builtin_nontemporal_store(z, out4 + idx);       // dwordx4 nt store
}

template <int H, int W, int BASE>
__device__ __forceinline__ void paint(const float* __restrict__ mask,
                                      float* __restrict__ row,
                                      int lh, int lw) {
  // Iterate the 28x28 source window; map to level coords; skip clipped.
  for (int c = threadIdx.x; c < G * G; c += 256) {
    const int si = c / G;            // compile-time 28 -> magic multiply
    const int sj = c - si * G;
    const int i = lh + si - CTR;
    const int j = lw + sj - CTR;
    if ((unsigned)i < (unsigned)H && (unsigned)j < (unsigned)W)
      row[BASE + i * W + j] = mask[c];
  }
}

__global__ __launch_bounds__(256) void paint_kernel(
    const int* __restrict__ pos, const float* __restrict__ mask,
    float* __restrict__ out) {
  const int inst = blockIdx.x;       // 512
  const int lvl  = blockIdx.y;       // 5

  // pos uniform per block -> scalar loads.
  const int p0 = pos[2 * inst];
  const int p1 = pos[2 * inst + 1];
  // Verified XLA chain: two separate f32 multiplies, RNE.
  const float x0 = (float)p0 * 0.005f;
  const float x1 = (float)p1 * 0.005f;

  float* row = out + (size_t)inst * ROW;
  switch (lvl) {
    case 0: paint<200, 200, 0>(mask, row,
              (int)rintf(x0 * 200.0f), (int)rintf(x1 * 200.0f)); break;
    case 1: paint<100, 100, 40000>(mask, row,
              (int)rintf(x0 * 100.0f), (int)rintf(x1 * 100.0f)); break;
    case 2: paint<50, 50, 50000>(mask, row,
              (int)rintf(x0 * 50.0f), (int)rintf(x1 * 50.0f)); break;
    case 3: paint<25, 25, 52500>(mask, row,
              (int)rintf(x0 * 25.0f), (int)rintf(x1 * 25.0f)); break;
    default: paint<13, 13, 53125>(mask, row,
              (int)rintf(x0 * 13.0f), (int)rintf(x1 * 13.0f)); break;
  }
}

extern "C" void kernel_launch(void* const* d_in, const int* in_sizes, int n_in,
                              void* d_out, int out_size, void* d_ws, size_t ws_size,
                              hipStream_t stream) {
  const int* pos = (const int*)d_in[0];          // (512,2) int32
  const float* mask = (const float*)d_in[1];     // (28,28) float32
  float* out = (float*)d_out;                    // 512*53294 float32

  fill_zero_nt_kernel<<<FILL_BLOCKS, 256, 0, stream>>>((vfloat4*)out);
  dim3 pgrid(512, 5);
  paint_kernel<<<pgrid, 256, 0, stream>>>(pos, mask, out);
}

// Round 15
// 121.149 us; speedup vs baseline: 1.0694x; 1.0694x over previous
//
#include <hip/hip_runtime.h>

// MaskPyramids R15: GRID-STRIDE zero-fill + sparse window paint.
// Index chain (VERIFIED bit-exact R11-R14, absmax=0.0): XLA rcp-multiply:
//   x = (float)p * 0.005f;  lh_L = (int)rintf(x * (float)H_L)
// R14 post-mortem: plain-f4 / memset-in-graph / nt-store fills ALL give
// ours ~= 48 us (clock-normalized) -> RFO is not the differentiator.
// Remaining delta vs rocclr's 6.3 TB/s fillBufferAligned: our fill used
// 26647 one-store-and-exit blocks (dispatch/setup-bound); rocclr uses a
// grid-stride loop, few blocks, many stores/thread. This round: fill as
// 2048 blocks x 256 threads x ~13 float4 stores (sustained issue).
//   expected: fill ~18-20 us + paint ~4 us -> dur ~93; if unchanged,
//   plain-store write ceiling ~2.5 TB/s is real -> fuse next round.

#define G 28
#define CTR 13
#define ROW 53294            // 40000+10000+2500+625+169 floats per instance
#define TOTAL_F4 6821632     // 512*ROW/4, exact
#define FILL_BLOCKS 2048
#define FILL_THREADS (FILL_BLOCKS * 256)   // 524288

typedef float vfloat4 __attribute__((ext_vector_type(4)));

__global__ __launch_bounds__(256) void fill_zero_gs_kernel(vfloat4* __restrict__ out4) {
  const int gid = blockIdx.x * 256 + threadIdx.x;
  const vfloat4 z = {0.f, 0.f, 0.f, 0.f};
  for (int i = gid; i < TOTAL_F4; i += FILL_THREADS)
    out4[i] = z;
}

template <int H, int W, int BASE>
__device__ __forceinline__ void paint(const float* __restrict__ mask,
                                      float* __restrict__ row,
                                      int lh, int lw) {
  // Iterate the 28x28 source window; map to level coords; skip clipped.
  for (int c = threadIdx.x; c < G * G; c += 256) {
    const int si = c / G;            // compile-time 28 -> magic multiply
    const int sj = c - si * G;
    const int i = lh + si - CTR;
    const int j = lw + sj - CTR;
    if ((unsigned)i < (unsigned)H && (unsigned)j < (unsigned)W)
      row[BASE + i * W + j] = mask[c];
  }
}

__global__ __launch_bounds__(256) void paint_kernel(
    const int* __restrict__ pos, const float* __restrict__ mask,
    float* __restrict__ out) {
  const int inst = blockIdx.x;       // 512
  const int lvl  = blockIdx.y;       // 5

  // pos uniform per block -> scalar loads.
  const int p0 = pos[2 * inst];
  const int p1 = pos[2 * inst + 1];
  // Verified XLA chain: two separate f32 multiplies, RNE.
  const float x0 = (float)p0 * 0.005f;
  const float x1 = (float)p1 * 0.005f;

  float* row = out + (size_t)inst * ROW;
  switch (lvl) {
    case 0: paint<200, 200, 0>(mask, row,
              (int)rintf(x0 * 200.0f), (int)rintf(x1 * 200.0f)); break;
    case 1: paint<100, 100, 40000>(mask, row,
              (int)rintf(x0 * 100.0f), (int)rintf(x1 * 100.0f)); break;
    case 2: paint<50, 50, 50000>(mask, row,
              (int)rintf(x0 * 50.0f), (int)rintf(x1 * 50.0f)); break;
    case 3: paint<25, 25, 52500>(mask, row,
              (int)rintf(x0 * 25.0f), (int)rintf(x1 * 25.0f)); break;
    default: paint<13, 13, 53125>(mask, row,
              (int)rintf(x0 * 13.0f), (int)rintf(x1 * 13.0f)); break;
  }
}

extern "C" void kernel_launch(void* const* d_in, const int* in_sizes, int n_in,
                              void* d_out, int out_size, void* d_ws, size_t ws_size,
                              hipStream_t stream) {
  const int* pos = (const int*)d_in[0];          // (512,2) int32
  const float* mask = (const float*)d_in[1];     // (28,28) float32
  float* out = (float*)d_out;                    // 512*53294 float32

  fill_zero_gs_kernel<<<FILL_BLOCKS, 256, 0, stream>>>((vfloat4*)out);
  dim3 pgrid(512, 5);
  paint_kernel<<<pgrid, 256, 0, stream>>>(pos, mask, out);
}

// Round 16
// 115.985 us; speedup vs baseline: 1.1170x; 1.0445x over previous
//
#include <hip/hip_runtime.h>

// MaskPyramids R16: FUSED one-kernel version - 512 blocks, one per
// instance. Each block zero-fills its own row then paints its 5 windows.
// Index chain (VERIFIED bit-exact R11-R15, absmax=0.0): XLA rcp-multiply:
//   x = (float)p * 0.005f;  lh_L = (int)rintf(x * (float)H_L)
// R15 post-mortem: one-shot/memset/nt/grid-stride fills all ~equal =>
// per-kernel store path was never the bottleneck; m13 proves plain f4
// stores reach ~6.3 TB/s. New model: harness fixed cost ~95 us, ours
// ~20-25. This round discriminates: fuse to ONE launch, block-local
// fill->sync->paint (paint RFOs hit L2 lines the block just wrote).
//   row = 53294 floats, starts at byte offset 8 (mod 16):
//   head float2 (8B-aligned) + 13323 float4 (16B-aligned).

#define G 28
#define CTR 13
#define ROW 53294           // 40000+10000+2500+625+169 floats per instance
#define BODY_F4 13323       // (ROW-2)/4, exact

template <int H, int W, int BASE>
__device__ __forceinline__ void paint(const float* __restrict__ mask,
                                      float* __restrict__ row,
                                      int lh, int lw) {
  for (int c = threadIdx.x; c < G * G; c += 256) {
    const int si = c / G;            // compile-time 28 -> magic multiply
    const int sj = c - si * G;
    const int i = lh + si - CTR;
    const int j = lw + sj - CTR;
    if ((unsigned)i < (unsigned)H && (unsigned)j < (unsigned)W)
      row[BASE + i * W + j] = mask[c];
  }
}

__global__ __launch_bounds__(256) void fused_kernel(
    const int* __restrict__ pos, const float* __restrict__ mask,
    float* __restrict__ out) {
  const int inst = blockIdx.x;       // 512 blocks, one instance each
  float* row = out + (size_t)inst * ROW;

  // ---- Phase 1: zero the row (float2 head + aligned float4 body) ----
  if (threadIdx.x == 0) *(float2*)row = make_float2(0.f, 0.f);
  float4* body = (float4*)(row + 2);               // 16B-aligned
  const float4 z = make_float4(0.f, 0.f, 0.f, 0.f);
  for (int i = threadIdx.x; i < BODY_F4; i += 256)
    body[i] = z;

  __syncthreads();   // row fully zeroed (block-local, no cross-block dep)

  // ---- Phase 2: paint the 5 windows (lines are L2/L1-resident now) ----
  const int p0 = pos[2 * inst];
  const int p1 = pos[2 * inst + 1];
  // Verified XLA chain: two separate f32 multiplies, RNE.
  const float x0 = (float)p0 * 0.005f;
  const float x1 = (float)p1 * 0.005f;

  paint<200, 200, 0>(mask, row,
      (int)rintf(x0 * 200.0f), (int)rintf(x1 * 200.0f));
  paint<100, 100, 40000>(mask, row,
      (int)rintf(x0 * 100.0f), (int)rintf(x1 * 100.0f));
  paint<50, 50, 50000>(mask, row,
      (int)rintf(x0 * 50.0f),  (int)rintf(x1 * 50.0f));
  paint<25, 25, 52500>(mask, row,
      (int)rintf(x0 * 25.0f),  (int)rintf(x1 * 25.0f));
  paint<13, 13, 53125>(mask, row,
      (int)rintf(x0 * 13.0f),  (int)rintf(x1 * 13.0f));
}

extern "C" void kernel_launch(void* const* d_in, const int* in_sizes, int n_in,
                              void* d_out, int out_size, void* d_ws, size_t ws_size,
                              hipStream_t stream) {
  const int* pos = (const int*)d_in[0];          // (512,2) int32
  const float* mask = (const float*)d_in[1];     // (28,28) float32
  float* out = (float*)d_out;                    // 512*53294 float32

  fused_kernel<<<512, 256, 0, stream>>>(pos, mask, out);
}